// Round 1
// baseline (1285.803 us; speedup 1.0000x reference)
//
#include <hip/hip_runtime.h>

#define N_NODES 100000
#define N_EDGES 1600000
#define D_IN 128
#define D_HID 128
#define D_OUT 64

// ---------------- degree histogram ----------------
__global__ void deg_kernel(const int* __restrict__ ei, int* __restrict__ deg) {
    int e = blockIdx.x * blockDim.x + threadIdx.x;
    if (e < N_EDGES) {
        int dst = ei[N_EDGES + e];
        atomicAdd(&deg[dst], 1);
    }
}

// ---------------- deg^(-1/2) ----------------
__global__ void dis_kernel(const int* __restrict__ deg, float* __restrict__ dis) {
    int i = blockIdx.x * blockDim.x + threadIdx.x;
    if (i < N_NODES) {
        int d = deg[i];
        dis[i] = (d > 0) ? rsqrtf((float)d) : 0.0f;
    }
}

// ---------------- GEMM1: C[N,128] = A[N,128] @ W[128,128] ----------------
// block = 256 threads, tile = 64 nodes x 128 cols, thread = 4 nodes x 8 cols
__global__ __launch_bounds__(256) void gemm1_kernel(const float* __restrict__ A,
                                                    const float* __restrict__ W,
                                                    float* __restrict__ C) {
    __shared__ float As[32][65];    // [k][node], padded
    __shared__ float Ws[32][128];   // [k][col]
    const int t  = threadIdx.x;
    const int tj = t & 15;   // col group -> cols tj*8 .. +7
    const int tn = t >> 4;   // node group -> nodes tn*4 .. +3
    const int node0 = blockIdx.x * 64;

    float acc[4][8];
#pragma unroll
    for (int i = 0; i < 4; i++)
#pragma unroll
        for (int j = 0; j < 8; j++) acc[i][j] = 0.0f;

    for (int kb = 0; kb < 4; ++kb) {
        // A tile: 64 nodes x 32 k. thread loads 8 consecutive k of one node.
        {
            int n   = t >> 2;          // 0..63
            int kk0 = (t & 3) * 8;     // 0,8,16,24
            int gn  = node0 + n;
            float4 v0 = make_float4(0, 0, 0, 0), v1 = v0;
            if (gn < N_NODES) {
                const float* p = A + (size_t)gn * 128 + kb * 32 + kk0;
                v0 = *(const float4*)p;
                v1 = *(const float4*)(p + 4);
            }
            As[kk0 + 0][n] = v0.x; As[kk0 + 1][n] = v0.y;
            As[kk0 + 2][n] = v0.z; As[kk0 + 3][n] = v0.w;
            As[kk0 + 4][n] = v1.x; As[kk0 + 5][n] = v1.y;
            As[kk0 + 6][n] = v1.z; As[kk0 + 7][n] = v1.w;
        }
        // W tile: rows kb*32..+31 are contiguous 4096 floats -> flat copy
        {
            const float4* Wg = (const float4*)(W + (size_t)kb * 32 * 128);
            float4* Wl = (float4*)(&Ws[0][0]);
#pragma unroll
            for (int i = 0; i < 4; i++) Wl[i * 256 + t] = Wg[i * 256 + t];
        }
        __syncthreads();
#pragma unroll
        for (int kk = 0; kk < 32; ++kk) {
            float4 a  = *(const float4*)&As[kk][tn * 4];
            float4 b0 = *(const float4*)&Ws[kk][tj * 8];
            float4 b1 = *(const float4*)&Ws[kk][tj * 8 + 4];
            float av[4] = {a.x, a.y, a.z, a.w};
            float bv[8] = {b0.x, b0.y, b0.z, b0.w, b1.x, b1.y, b1.z, b1.w};
#pragma unroll
            for (int i = 0; i < 4; i++)
#pragma unroll
                for (int j = 0; j < 8; j++) acc[i][j] += av[i] * bv[j];
        }
        __syncthreads();
    }
#pragma unroll
    for (int i = 0; i < 4; i++) {
        int gn = node0 + tn * 4 + i;
        if (gn < N_NODES) {
            float* p = C + (size_t)gn * 128 + tj * 8;
            *(float4*)p       = make_float4(acc[i][0], acc[i][1], acc[i][2], acc[i][3]);
            *(float4*)(p + 4) = make_float4(acc[i][4], acc[i][5], acc[i][6], acc[i][7]);
        }
    }
}

// ---------------- GEMM2: C[N,64] = relu(Agg[N,128]+b1) @ W2[128,64] ----------------
// block = 256, tile = 64 nodes x 64 cols, thread = 4 nodes x 4 cols
__global__ __launch_bounds__(256) void gemm2_kernel(const float* __restrict__ Agg,
                                                    const float* __restrict__ b1,
                                                    const float* __restrict__ W2,
                                                    float* __restrict__ C) {
    __shared__ float As[32][65];
    __shared__ float Ws[32][64];
    const int t  = threadIdx.x;
    const int tj = t & 15;   // cols tj*4 .. +3
    const int tn = t >> 4;   // nodes tn*4 .. +3
    const int node0 = blockIdx.x * 64;

    float acc[4][4];
#pragma unroll
    for (int i = 0; i < 4; i++)
#pragma unroll
        for (int j = 0; j < 4; j++) acc[i][j] = 0.0f;

    for (int kb = 0; kb < 4; ++kb) {
        {
            int n   = t >> 2;
            int kk0 = (t & 3) * 8;
            int gn  = node0 + n;
            float v[8];
            if (gn < N_NODES) {
                const float* p = Agg + (size_t)gn * 128 + kb * 32 + kk0;
                float4 v0 = *(const float4*)p;
                float4 v1 = *(const float4*)(p + 4);
                const float* bp = b1 + kb * 32 + kk0;
                v[0] = v0.x + bp[0]; v[1] = v0.y + bp[1];
                v[2] = v0.z + bp[2]; v[3] = v0.w + bp[3];
                v[4] = v1.x + bp[4]; v[5] = v1.y + bp[5];
                v[6] = v1.z + bp[6]; v[7] = v1.w + bp[7];
#pragma unroll
                for (int i = 0; i < 8; i++) v[i] = fmaxf(v[i], 0.0f);
            } else {
#pragma unroll
                for (int i = 0; i < 8; i++) v[i] = 0.0f;
            }
#pragma unroll
            for (int i = 0; i < 8; i++) As[kk0 + i][n] = v[i];
        }
        {
            const float4* Wg = (const float4*)(W2 + (size_t)kb * 32 * 64);
            float4* Wl = (float4*)(&Ws[0][0]);
#pragma unroll
            for (int i = 0; i < 2; i++) Wl[i * 256 + t] = Wg[i * 256 + t];
        }
        __syncthreads();
#pragma unroll
        for (int kk = 0; kk < 32; ++kk) {
            float4 a = *(const float4*)&As[kk][tn * 4];
            float4 b = *(const float4*)&Ws[kk][tj * 4];
            float av[4] = {a.x, a.y, a.z, a.w};
            float bv[4] = {b.x, b.y, b.z, b.w};
#pragma unroll
            for (int i = 0; i < 4; i++)
#pragma unroll
                for (int j = 0; j < 4; j++) acc[i][j] += av[i] * bv[j];
        }
        __syncthreads();
    }
#pragma unroll
    for (int i = 0; i < 4; i++) {
        int gn = node0 + tn * 4 + i;
        if (gn < N_NODES) {
            float* p = C + (size_t)gn * 64 + tj * 4;
            *(float4*)p = make_float4(acc[i][0], acc[i][1], acc[i][2], acc[i][3]);
        }
    }
}

// ---------------- edge scatter, width 128 ----------------
// grid covers exactly E*128 threads; 2 edges per 256-thread block
__global__ void edge1_kernel(const int* __restrict__ ei, const float* __restrict__ dis,
                             const float* __restrict__ h, float* __restrict__ agg) {
    long long gid = (long long)blockIdx.x * 256 + threadIdx.x;
    int e = (int)(gid >> 7);
    int j = (int)(gid & 127);
    int src = ei[e];
    int dst = ei[N_EDGES + e];
    float norm = dis[src] * dis[dst];
    atomicAdd(&agg[(size_t)dst * 128 + j], h[(size_t)src * 128 + j] * norm);
}

// ---------------- edge scatter, width 64 ----------------
__global__ void edge2_kernel(const int* __restrict__ ei, const float* __restrict__ dis,
                             const float* __restrict__ h, float* __restrict__ out) {
    long long gid = (long long)blockIdx.x * 256 + threadIdx.x;
    int e = (int)(gid >> 6);
    int j = (int)(gid & 63);
    int src = ei[e];
    int dst = ei[N_EDGES + e];
    float norm = dis[src] * dis[dst];
    atomicAdd(&out[(size_t)dst * 64 + j], h[(size_t)src * 64 + j] * norm);
}

// ---------------- out = broadcast(b2) ----------------
__global__ void init_out_kernel(const float* __restrict__ b2, float* __restrict__ out) {
    int i = blockIdx.x * 256 + threadIdx.x;
    if (i < N_NODES * 64) out[i] = b2[i & 63];
}

extern "C" void kernel_launch(void* const* d_in, const int* in_sizes, int n_in,
                              void* d_out, int out_size, void* d_ws, size_t ws_size,
                              hipStream_t stream) {
    const float* x  = (const float*)d_in[0];
    const int*   ei = (const int*)d_in[1];
    const float* W1 = (const float*)d_in[2];
    const float* b1 = (const float*)d_in[3];
    const float* W2 = (const float*)d_in[4];
    const float* b2 = (const float*)d_in[5];
    float* out = (float*)d_out;

    char* ws = (char*)d_ws;
    int*   deg  = (int*)ws;                                   // 400 KB
    float* dis  = (float*)(ws + (size_t)512 * 1024);          // 400 KB
    float* h1   = (float*)(ws + (size_t)1024 * 1024);         // 51.2 MB
    float* agg1 = (float*)(ws + (size_t)1024 * 1024 + (size_t)N_NODES * 128 * 4);
    float* h2   = h1;  // h1 dead after edge1; reuse for layer-2 transform

    hipMemsetAsync(deg, 0, N_NODES * sizeof(int), stream);
    hipMemsetAsync(agg1, 0, (size_t)N_NODES * 128 * sizeof(float), stream);

    deg_kernel<<<(N_EDGES + 255) / 256, 256, 0, stream>>>(ei, deg);
    dis_kernel<<<(N_NODES + 255) / 256, 256, 0, stream>>>(deg, dis);
    gemm1_kernel<<<(N_NODES + 63) / 64, 256, 0, stream>>>(x, W1, h1);
    edge1_kernel<<<N_EDGES * 128 / 256, 256, 0, stream>>>(ei, dis, h1, agg1);
    gemm2_kernel<<<(N_NODES + 63) / 64, 256, 0, stream>>>(agg1, b1, W2, h2);
    init_out_kernel<<<N_NODES * 64 / 256, 256, 0, stream>>>(b2, out);
    edge2_kernel<<<N_EDGES * 64 / 256, 256, 0, stream>>>(ei, dis, h2, out);
}

// Round 2
// 666.352 us; speedup vs baseline: 1.9296x; 1.9296x over previous
//
#include <hip/hip_runtime.h>

#define N_NODES 100000
#define N_EDGES 1600000
#define NBLK 391   // ceil(N_NODES/256)

// ---------------- degree histogram ----------------
__global__ void deg_kernel(const int* __restrict__ ei, int* __restrict__ deg) {
    int e = blockIdx.x * blockDim.x + threadIdx.x;
    if (e < N_EDGES) atomicAdd(&deg[ei[N_EDGES + e]], 1);
}

// ---------------- deg^(-1/2) ----------------
__global__ void dis_kernel(const int* __restrict__ deg, float* __restrict__ dis) {
    int i = blockIdx.x * blockDim.x + threadIdx.x;
    if (i < N_NODES) {
        int d = deg[i];
        dis[i] = (d > 0) ? rsqrtf((float)d) : 0.0f;
    }
}

// ---------------- exclusive scan, 2-level ----------------
__global__ void scan_block(const int* __restrict__ deg, int* __restrict__ offs,
                           int* __restrict__ bsum) {
    __shared__ int s[256];
    int tid = threadIdx.x;
    int i = blockIdx.x * 256 + tid;
    int v = (i < N_NODES) ? deg[i] : 0;
    s[tid] = v;
    __syncthreads();
#pragma unroll
    for (int off = 1; off < 256; off <<= 1) {
        int t = (tid >= off) ? s[tid - off] : 0;
        __syncthreads();
        s[tid] += t;
        __syncthreads();
    }
    if (i < N_NODES) offs[i] = s[tid] - v;      // exclusive
    if (tid == 255) bsum[blockIdx.x] = s[255];  // block total
}

__global__ void scan_top(int* __restrict__ bsum) {
    __shared__ int s[512];
    int tid = threadIdx.x;
    int v = (tid < NBLK) ? bsum[tid] : 0;
    s[tid] = v;
    __syncthreads();
#pragma unroll
    for (int off = 1; off < 512; off <<= 1) {
        int t = (tid >= off) ? s[tid - off] : 0;
        __syncthreads();
        s[tid] += t;
        __syncthreads();
    }
    if (tid < NBLK) bsum[tid] = s[tid] - v;     // exclusive
}

__global__ void scan_add(int* __restrict__ offs, const int* __restrict__ bsum) {
    int i = blockIdx.x * 256 + threadIdx.x;
    if (i < N_NODES) offs[i] += bsum[i >> 8];
}

// ---------------- CSR bucket fill (sorted src per dst) ----------------
__global__ void fill_kernel(const int* __restrict__ ei, const int* __restrict__ offs,
                            int* __restrict__ cur, int* __restrict__ srcn) {
    int e = blockIdx.x * 256 + threadIdx.x;
    if (e < N_EDGES) {
        int src = ei[e];
        int dst = ei[N_EDGES + e];
        int pos = offs[dst] + atomicAdd(&cur[dst], 1);
        srcn[pos] = src;
    }
}

// ---------------- GEMM1: C[N,128] = A[N,128] @ W[128,128] ----------------
__global__ __launch_bounds__(256) void gemm1_kernel(const float* __restrict__ A,
                                                    const float* __restrict__ W,
                                                    float* __restrict__ C) {
    __shared__ float As[32][65];
    __shared__ float Ws[32][128];
    const int t  = threadIdx.x;
    const int tj = t & 15;
    const int tn = t >> 4;
    const int node0 = blockIdx.x * 64;

    float acc[4][8];
#pragma unroll
    for (int i = 0; i < 4; i++)
#pragma unroll
        for (int j = 0; j < 8; j++) acc[i][j] = 0.0f;

    for (int kb = 0; kb < 4; ++kb) {
        {
            int n   = t >> 2;
            int kk0 = (t & 3) * 8;
            int gn  = node0 + n;
            float4 v0 = make_float4(0, 0, 0, 0), v1 = v0;
            if (gn < N_NODES) {
                const float* p = A + (size_t)gn * 128 + kb * 32 + kk0;
                v0 = *(const float4*)p;
                v1 = *(const float4*)(p + 4);
            }
            As[kk0 + 0][n] = v0.x; As[kk0 + 1][n] = v0.y;
            As[kk0 + 2][n] = v0.z; As[kk0 + 3][n] = v0.w;
            As[kk0 + 4][n] = v1.x; As[kk0 + 5][n] = v1.y;
            As[kk0 + 6][n] = v1.z; As[kk0 + 7][n] = v1.w;
        }
        {
            const float4* Wg = (const float4*)(W + (size_t)kb * 32 * 128);
            float4* Wl = (float4*)(&Ws[0][0]);
#pragma unroll
            for (int i = 0; i < 4; i++) Wl[i * 256 + t] = Wg[i * 256 + t];
        }
        __syncthreads();
#pragma unroll
        for (int kk = 0; kk < 32; ++kk) {
            float4 a  = *(const float4*)&As[kk][tn * 4];
            float4 b0 = *(const float4*)&Ws[kk][tj * 8];
            float4 b1 = *(const float4*)&Ws[kk][tj * 8 + 4];
            float av[4] = {a.x, a.y, a.z, a.w};
            float bv[8] = {b0.x, b0.y, b0.z, b0.w, b1.x, b1.y, b1.z, b1.w};
#pragma unroll
            for (int i = 0; i < 4; i++)
#pragma unroll
                for (int j = 0; j < 8; j++) acc[i][j] += av[i] * bv[j];
        }
        __syncthreads();
    }
#pragma unroll
    for (int i = 0; i < 4; i++) {
        int gn = node0 + tn * 4 + i;
        if (gn < N_NODES) {
            float* p = C + (size_t)gn * 128 + tj * 8;
            *(float4*)p       = make_float4(acc[i][0], acc[i][1], acc[i][2], acc[i][3]);
            *(float4*)(p + 4) = make_float4(acc[i][4], acc[i][5], acc[i][6], acc[i][7]);
        }
    }
}

// ---------------- GEMM2: C[N,64] = relu(Agg[N,128]+b1) @ W2[128,64] ----------------
__global__ __launch_bounds__(256) void gemm2_kernel(const float* __restrict__ Agg,
                                                    const float* __restrict__ b1,
                                                    const float* __restrict__ W2,
                                                    float* __restrict__ C) {
    __shared__ float As[32][65];
    __shared__ float Ws[32][64];
    const int t  = threadIdx.x;
    const int tj = t & 15;
    const int tn = t >> 4;
    const int node0 = blockIdx.x * 64;

    float acc[4][4];
#pragma unroll
    for (int i = 0; i < 4; i++)
#pragma unroll
        for (int j = 0; j < 4; j++) acc[i][j] = 0.0f;

    for (int kb = 0; kb < 4; ++kb) {
        {
            int n   = t >> 2;
            int kk0 = (t & 3) * 8;
            int gn  = node0 + n;
            float v[8];
            if (gn < N_NODES) {
                const float* p = Agg + (size_t)gn * 128 + kb * 32 + kk0;
                float4 v0 = *(const float4*)p;
                float4 v1 = *(const float4*)(p + 4);
                const float* bp = b1 + kb * 32 + kk0;
                v[0] = v0.x + bp[0]; v[1] = v0.y + bp[1];
                v[2] = v0.z + bp[2]; v[3] = v0.w + bp[3];
                v[4] = v1.x + bp[4]; v[5] = v1.y + bp[5];
                v[6] = v1.z + bp[6]; v[7] = v1.w + bp[7];
#pragma unroll
                for (int i = 0; i < 8; i++) v[i] = fmaxf(v[i], 0.0f);
            } else {
#pragma unroll
                for (int i = 0; i < 8; i++) v[i] = 0.0f;
            }
#pragma unroll
            for (int i = 0; i < 8; i++) As[kk0 + i][n] = v[i];
        }
        {
            const float4* Wg = (const float4*)(W2 + (size_t)kb * 32 * 64);
            float4* Wl = (float4*)(&Ws[0][0]);
#pragma unroll
            for (int i = 0; i < 2; i++) Wl[i * 256 + t] = Wg[i * 256 + t];
        }
        __syncthreads();
#pragma unroll
        for (int kk = 0; kk < 32; ++kk) {
            float4 a = *(const float4*)&As[kk][tn * 4];
            float4 b = *(const float4*)&Ws[kk][tj * 4];
            float av[4] = {a.x, a.y, a.z, a.w};
            float bv[4] = {b.x, b.y, b.z, b.w};
#pragma unroll
            for (int i = 0; i < 4; i++)
#pragma unroll
                for (int j = 0; j < 4; j++) acc[i][j] += av[i] * bv[j];
        }
        __syncthreads();
    }
#pragma unroll
    for (int i = 0; i < 4; i++) {
        int gn = node0 + tn * 4 + i;
        if (gn < N_NODES) {
            float* p = C + (size_t)gn * 64 + tj * 4;
            *(float4*)p = make_float4(acc[i][0], acc[i][1], acc[i][2], acc[i][3]);
        }
    }
}

// ---------------- CSR aggregation, width 128: one wave per node ----------------
// lane handles cols 2*lane, 2*lane+1 -> 512B coalesced gather per neighbor
__global__ __launch_bounds__(256) void agg1_kernel(const int* __restrict__ srcn,
                                                   const int* __restrict__ offs,
                                                   const int* __restrict__ deg,
                                                   const float* __restrict__ dis,
                                                   const float* __restrict__ h,
                                                   float* __restrict__ agg) {
    int wave = (blockIdx.x * 256 + threadIdx.x) >> 6;
    int lane = threadIdx.x & 63;
    if (wave >= N_NODES) return;
    int beg = offs[wave];
    int d   = deg[wave];
    float dv = dis[wave];
    float2 acc = make_float2(0.0f, 0.0f);
    for (int k = 0; k < d; ++k) {
        int src = srcn[beg + k];
        float w = dis[src] * dv;
        float2 v = ((const float2*)(h + (size_t)src * 128))[lane];
        acc.x += w * v.x;
        acc.y += w * v.y;
    }
    ((float2*)(agg + (size_t)wave * 128))[lane] = acc;
}

// ---------------- CSR aggregation, width 64, + b2 -> out ----------------
__global__ __launch_bounds__(256) void agg2_kernel(const int* __restrict__ srcn,
                                                   const int* __restrict__ offs,
                                                   const int* __restrict__ deg,
                                                   const float* __restrict__ dis,
                                                   const float* __restrict__ h,
                                                   const float* __restrict__ b2,
                                                   float* __restrict__ out) {
    int wave = (blockIdx.x * 256 + threadIdx.x) >> 6;
    int lane = threadIdx.x & 63;
    if (wave >= N_NODES) return;
    int beg = offs[wave];
    int d   = deg[wave];
    float dv = dis[wave];
    float acc = 0.0f;
    for (int k = 0; k < d; ++k) {
        int src = srcn[beg + k];
        float w = dis[src] * dv;
        acc += w * h[(size_t)src * 64 + lane];
    }
    out[(size_t)wave * 64 + lane] = acc + b2[lane];
}

extern "C" void kernel_launch(void* const* d_in, const int* in_sizes, int n_in,
                              void* d_out, int out_size, void* d_ws, size_t ws_size,
                              hipStream_t stream) {
    const float* x  = (const float*)d_in[0];
    const int*   ei = (const int*)d_in[1];
    const float* W1 = (const float*)d_in[2];
    const float* b1 = (const float*)d_in[3];
    const float* W2 = (const float*)d_in[4];
    const float* b2 = (const float*)d_in[5];
    float* out = (float*)d_out;

    char* ws = (char*)d_ws;
    int*   deg  = (int*)(ws);                          // 400 KB   @ 0
    int*   cur  = (int*)(ws + (size_t)512 * 1024);     // 400 KB   @ 0.5 MB
    int*   offs = (int*)(ws + (size_t)1024 * 1024);    // 400 KB   @ 1.0 MB
    float* dis  = (float*)(ws + (size_t)1536 * 1024);  // 400 KB   @ 1.5 MB
    int*   bsum = (int*)(ws + (size_t)2048 * 1024);    // 2 KB     @ 2.0 MB
    int*   srcn = (int*)(ws + (size_t)2560 * 1024);    // 6.4 MB   @ 2.5 MB
    float* h1   = (float*)(ws + (size_t)9216 * 1024);  // 51.2 MB  @ 9.0 MB
    float* agg1 = (float*)(ws + (size_t)9216 * 1024 + (size_t)N_NODES * 128 * 4);
    float* h2   = h1;  // h1 dead after agg1; gemm2 writes h2 there

    // zero deg + cur in one shot (they occupy [0, 1MB))
    hipMemsetAsync(ws, 0, (size_t)1024 * 1024, stream);

    deg_kernel<<<(N_EDGES + 255) / 256, 256, 0, stream>>>(ei, deg);
    dis_kernel<<<(N_NODES + 255) / 256, 256, 0, stream>>>(deg, dis);
    scan_block<<<NBLK, 256, 0, stream>>>(deg, offs, bsum);
    scan_top<<<1, 512, 0, stream>>>(bsum);
    scan_add<<<NBLK, 256, 0, stream>>>(offs, bsum);
    fill_kernel<<<(N_EDGES + 255) / 256, 256, 0, stream>>>(ei, offs, cur, srcn);
    gemm1_kernel<<<(N_NODES + 63) / 64, 256, 0, stream>>>(x, W1, h1);
    agg1_kernel<<<(N_NODES * 64 + 255) / 256, 256, 0, stream>>>(srcn, offs, deg, dis, h1, agg1);
    gemm2_kernel<<<(N_NODES + 63) / 64, 256, 0, stream>>>(agg1, b1, W2, h2);
    agg2_kernel<<<(N_NODES * 64 + 255) / 256, 256, 0, stream>>>(srcn, offs, deg, dis, h2, b2, out);
}

// Round 3
// 512.447 us; speedup vs baseline: 2.5091x; 1.3003x over previous
//
#include <hip/hip_runtime.h>

#define N_NODES 100000
#define N_EDGES 1600000
#define NBLK 391   // ceil(N_NODES/256)

// pack two fp32 -> two bf16 (RNE) in one uint (a=low, b=high)
__device__ inline unsigned bfpack(float a, float b) {
    unsigned ua = __builtin_bit_cast(unsigned, a);
    unsigned ub = __builtin_bit_cast(unsigned, b);
    ua = (ua + 0x7FFF + ((ua >> 16) & 1)) >> 16;
    ub = (ub + 0x7FFF + ((ub >> 16) & 1)) >> 16;
    return ua | (ub << 16);
}

// ---------------- degree histogram ----------------
__global__ void deg_kernel(const int* __restrict__ ei, int* __restrict__ deg) {
    int e = blockIdx.x * blockDim.x + threadIdx.x;
    if (e < N_EDGES) atomicAdd(&deg[ei[N_EDGES + e]], 1);
}

// ---------------- deg^(-1/2) ----------------
__global__ void dis_kernel(const int* __restrict__ deg, float* __restrict__ dis) {
    int i = blockIdx.x * blockDim.x + threadIdx.x;
    if (i < N_NODES) {
        int d = deg[i];
        dis[i] = (d > 0) ? rsqrtf((float)d) : 0.0f;
    }
}

// ---------------- exclusive scan, 2-level ----------------
__global__ void scan_block(const int* __restrict__ deg, int* __restrict__ offs,
                           int* __restrict__ bsum) {
    __shared__ int s[256];
    int tid = threadIdx.x;
    int i = blockIdx.x * 256 + tid;
    int v = (i < N_NODES) ? deg[i] : 0;
    s[tid] = v;
    __syncthreads();
#pragma unroll
    for (int off = 1; off < 256; off <<= 1) {
        int t = (tid >= off) ? s[tid - off] : 0;
        __syncthreads();
        s[tid] += t;
        __syncthreads();
    }
    if (i < N_NODES) offs[i] = s[tid] - v;
    if (tid == 255) bsum[blockIdx.x] = s[255];
}

__global__ void scan_top(int* __restrict__ bsum) {
    __shared__ int s[512];
    int tid = threadIdx.x;
    int v = (tid < NBLK) ? bsum[tid] : 0;
    s[tid] = v;
    __syncthreads();
#pragma unroll
    for (int off = 1; off < 512; off <<= 1) {
        int t = (tid >= off) ? s[tid - off] : 0;
        __syncthreads();
        s[tid] += t;
        __syncthreads();
    }
    if (tid < NBLK) bsum[tid] = s[tid] - v;
}

__global__ void scan_add(int* __restrict__ offs, const int* __restrict__ bsum) {
    int i = blockIdx.x * 256 + threadIdx.x;
    if (i < N_NODES) offs[i] += bsum[i >> 8];
}

// ---------------- CSR bucket fill ----------------
__global__ void fill_kernel(const int* __restrict__ ei, const int* __restrict__ offs,
                            int* __restrict__ cur, int* __restrict__ srcn) {
    int e = blockIdx.x * 256 + threadIdx.x;
    if (e < N_EDGES) {
        int src = ei[e];
        int dst = ei[N_EDGES + e];
        int pos = offs[dst] + atomicAdd(&cur[dst], 1);
        srcn[pos] = src;
    }
}

// ---------------- GEMM1: h1b[N,128](bf16) = (A[N,128] @ W[128,128]) * dis[n] ----------------
__global__ __launch_bounds__(256) void gemm1_kernel(const float* __restrict__ A,
                                                    const float* __restrict__ W,
                                                    const float* __restrict__ dis,
                                                    unsigned short* __restrict__ h1b) {
    __shared__ float As[32][65];
    __shared__ float Ws[32][128];
    const int t  = threadIdx.x;
    const int tj = t & 15;
    const int tn = t >> 4;
    const int node0 = blockIdx.x * 64;

    float acc[4][8];
#pragma unroll
    for (int i = 0; i < 4; i++)
#pragma unroll
        for (int j = 0; j < 8; j++) acc[i][j] = 0.0f;

    for (int kb = 0; kb < 4; ++kb) {
        {
            int n   = t >> 2;
            int kk0 = (t & 3) * 8;
            int gn  = node0 + n;
            float4 v0 = make_float4(0, 0, 0, 0), v1 = v0;
            if (gn < N_NODES) {
                const float* p = A + (size_t)gn * 128 + kb * 32 + kk0;
                v0 = *(const float4*)p;
                v1 = *(const float4*)(p + 4);
            }
            As[kk0 + 0][n] = v0.x; As[kk0 + 1][n] = v0.y;
            As[kk0 + 2][n] = v0.z; As[kk0 + 3][n] = v0.w;
            As[kk0 + 4][n] = v1.x; As[kk0 + 5][n] = v1.y;
            As[kk0 + 6][n] = v1.z; As[kk0 + 7][n] = v1.w;
        }
        {
            const float4* Wg = (const float4*)(W + (size_t)kb * 32 * 128);
            float4* Wl = (float4*)(&Ws[0][0]);
#pragma unroll
            for (int i = 0; i < 4; i++) Wl[i * 256 + t] = Wg[i * 256 + t];
        }
        __syncthreads();
#pragma unroll
        for (int kk = 0; kk < 32; ++kk) {
            float4 a  = *(const float4*)&As[kk][tn * 4];
            float4 b0 = *(const float4*)&Ws[kk][tj * 8];
            float4 b1 = *(const float4*)&Ws[kk][tj * 8 + 4];
            float av[4] = {a.x, a.y, a.z, a.w};
            float bv[8] = {b0.x, b0.y, b0.z, b0.w, b1.x, b1.y, b1.z, b1.w};
#pragma unroll
            for (int i = 0; i < 4; i++)
#pragma unroll
                for (int j = 0; j < 8; j++) acc[i][j] += av[i] * bv[j];
        }
        __syncthreads();
    }
#pragma unroll
    for (int i = 0; i < 4; i++) {
        int gn = node0 + tn * 4 + i;
        if (gn < N_NODES) {
            float dv = dis[gn];
            uint4 o;
            o.x = bfpack(acc[i][0] * dv, acc[i][1] * dv);
            o.y = bfpack(acc[i][2] * dv, acc[i][3] * dv);
            o.z = bfpack(acc[i][4] * dv, acc[i][5] * dv);
            o.w = bfpack(acc[i][6] * dv, acc[i][7] * dv);
            *(uint4*)(h1b + (size_t)gn * 128 + tj * 8) = o;
        }
    }
}

// ---------------- GEMM2: h2s[N,64] = (relu(Agg+b1) @ W2) * dis[n] ----------------
__global__ __launch_bounds__(256) void gemm2_kernel(const float* __restrict__ Agg,
                                                    const float* __restrict__ b1,
                                                    const float* __restrict__ W2,
                                                    const float* __restrict__ dis,
                                                    float* __restrict__ h2s) {
    __shared__ float As[32][65];
    __shared__ float Ws[32][64];
    const int t  = threadIdx.x;
    const int tj = t & 15;
    const int tn = t >> 4;
    const int node0 = blockIdx.x * 64;

    float acc[4][4];
#pragma unroll
    for (int i = 0; i < 4; i++)
#pragma unroll
        for (int j = 0; j < 4; j++) acc[i][j] = 0.0f;

    for (int kb = 0; kb < 4; ++kb) {
        {
            int n   = t >> 2;
            int kk0 = (t & 3) * 8;
            int gn  = node0 + n;
            float v[8];
            if (gn < N_NODES) {
                const float* p = Agg + (size_t)gn * 128 + kb * 32 + kk0;
                float4 v0 = *(const float4*)p;
                float4 v1 = *(const float4*)(p + 4);
                const float* bp = b1 + kb * 32 + kk0;
                v[0] = v0.x + bp[0]; v[1] = v0.y + bp[1];
                v[2] = v0.z + bp[2]; v[3] = v0.w + bp[3];
                v[4] = v1.x + bp[4]; v[5] = v1.y + bp[5];
                v[6] = v1.z + bp[6]; v[7] = v1.w + bp[7];
#pragma unroll
                for (int i = 0; i < 8; i++) v[i] = fmaxf(v[i], 0.0f);
            } else {
#pragma unroll
                for (int i = 0; i < 8; i++) v[i] = 0.0f;
            }
#pragma unroll
            for (int i = 0; i < 8; i++) As[kk0 + i][n] = v[i];
        }
        {
            const float4* Wg = (const float4*)(W2 + (size_t)kb * 32 * 64);
            float4* Wl = (float4*)(&Ws[0][0]);
#pragma unroll
            for (int i = 0; i < 2; i++) Wl[i * 256 + t] = Wg[i * 256 + t];
        }
        __syncthreads();
#pragma unroll
        for (int kk = 0; kk < 32; ++kk) {
            float4 a = *(const float4*)&As[kk][tn * 4];
            float4 b = *(const float4*)&Ws[kk][tj * 4];
            float av[4] = {a.x, a.y, a.z, a.w};
            float bv[4] = {b.x, b.y, b.z, b.w};
#pragma unroll
            for (int i = 0; i < 4; i++)
#pragma unroll
                for (int j = 0; j < 4; j++) acc[i][j] += av[i] * bv[j];
        }
        __syncthreads();
    }
#pragma unroll
    for (int i = 0; i < 4; i++) {
        int gn = node0 + tn * 4 + i;
        if (gn < N_NODES) {
            float dv = dis[gn];
            float* p = h2s + (size_t)gn * 64 + tj * 4;
            *(float4*)p = make_float4(acc[i][0] * dv, acc[i][1] * dv,
                                      acc[i][2] * dv, acc[i][3] * dv);
        }
    }
}

// ---------------- CSR aggregation, width 128, bf16 gather: one wave per node ----------------
// h1b rows premultiplied by dis[src]; lane loads one uint (2 bf16) = 256B/row coalesced
__global__ __launch_bounds__(256) void agg1_kernel(const int* __restrict__ srcn,
                                                   const int* __restrict__ offs,
                                                   const int* __restrict__ deg,
                                                   const float* __restrict__ dis,
                                                   const unsigned* __restrict__ h1b,
                                                   float* __restrict__ agg) {
    int wave = (blockIdx.x * 256 + threadIdx.x) >> 6;
    int lane = threadIdx.x & 63;
    if (wave >= N_NODES) return;
    int beg = offs[wave];
    int d   = deg[wave];
    float dv = dis[wave];
    float ax = 0.0f, ay = 0.0f;
#pragma unroll 4
    for (int k = 0; k < d; ++k) {
        int src = srcn[beg + k];
        unsigned v = h1b[(size_t)src * 64 + lane];
        ax += __builtin_bit_cast(float, v << 16);
        ay += __builtin_bit_cast(float, v & 0xFFFF0000u);
    }
    ((float2*)(agg + (size_t)wave * 128))[lane] = make_float2(dv * ax, dv * ay);
}

// ---------------- CSR aggregation, width 64 fp32, + b2 -> out ----------------
__global__ __launch_bounds__(256) void agg2_kernel(const int* __restrict__ srcn,
                                                   const int* __restrict__ offs,
                                                   const int* __restrict__ deg,
                                                   const float* __restrict__ dis,
                                                   const float* __restrict__ h2s,
                                                   const float* __restrict__ b2,
                                                   float* __restrict__ out) {
    int wave = (blockIdx.x * 256 + threadIdx.x) >> 6;
    int lane = threadIdx.x & 63;
    if (wave >= N_NODES) return;
    int beg = offs[wave];
    int d   = deg[wave];
    float dv = dis[wave];
    float acc = 0.0f;
#pragma unroll 4
    for (int k = 0; k < d; ++k) {
        int src = srcn[beg + k];
        acc += h2s[(size_t)src * 64 + lane];
    }
    out[(size_t)wave * 64 + lane] = dv * acc + b2[lane];
}

extern "C" void kernel_launch(void* const* d_in, const int* in_sizes, int n_in,
                              void* d_out, int out_size, void* d_ws, size_t ws_size,
                              hipStream_t stream) {
    const float* x  = (const float*)d_in[0];
    const int*   ei = (const int*)d_in[1];
    const float* W1 = (const float*)d_in[2];
    const float* b1 = (const float*)d_in[3];
    const float* W2 = (const float*)d_in[4];
    const float* b2 = (const float*)d_in[5];
    float* out = (float*)d_out;

    char* ws = (char*)d_ws;
    int*   deg  = (int*)(ws);                          // 400 KB   @ 0
    int*   cur  = (int*)(ws + (size_t)512 * 1024);     // 400 KB   @ 0.5 MB
    int*   offs = (int*)(ws + (size_t)1024 * 1024);    // 400 KB   @ 1.0 MB
    float* dis  = (float*)(ws + (size_t)1536 * 1024);  // 400 KB   @ 1.5 MB
    int*   bsum = (int*)(ws + (size_t)2048 * 1024);    // 2 KB     @ 2.0 MB
    int*   srcn = (int*)(ws + (size_t)2560 * 1024);    // 6.4 MB   @ 2.5 MB
    unsigned short* h1b = (unsigned short*)(ws + (size_t)9216 * 1024);  // 25.6 MB @ 9 MB
    float* h2s  = (float*)(ws + (size_t)9216 * 1024);  // 25.6 MB @ 9 MB (aliases h1b; h1b dead)
    float* agg1 = (float*)(ws + (size_t)36 * 1024 * 1024);  // 51.2 MB @ 36 MB

    hipMemsetAsync(ws, 0, (size_t)1024 * 1024, stream);  // deg + cur

    deg_kernel<<<(N_EDGES + 255) / 256, 256, 0, stream>>>(ei, deg);
    dis_kernel<<<(N_NODES + 255) / 256, 256, 0, stream>>>(deg, dis);
    scan_block<<<NBLK, 256, 0, stream>>>(deg, offs, bsum);
    scan_top<<<1, 512, 0, stream>>>(bsum);
    scan_add<<<NBLK, 256, 0, stream>>>(offs, bsum);
    fill_kernel<<<(N_EDGES + 255) / 256, 256, 0, stream>>>(ei, offs, cur, srcn);
    gemm1_kernel<<<(N_NODES + 63) / 64, 256, 0, stream>>>(x, W1, dis, h1b);
    agg1_kernel<<<(N_NODES * 64 + 255) / 256, 256, 0, stream>>>(srcn, offs, deg, dis,
                                                                (const unsigned*)h1b, agg1);
    gemm2_kernel<<<(N_NODES + 63) / 64, 256, 0, stream>>>(agg1, b1, W2, dis, h2s);
    agg2_kernel<<<(N_NODES * 64 + 255) / 256, 256, 0, stream>>>(srcn, offs, deg, dis, h2s, b2, out);
}

// Round 4
// 451.702 us; speedup vs baseline: 2.8466x; 1.1345x over previous
//
#include <hip/hip_runtime.h>

#define N_NODES 100000
#define N_EDGES 1600000
#define NBLK 391    // ceil(N_NODES/256) for scan
#define NBUCK 391   // dst buckets of 256 nodes (dst>>8)
#define CHUNKA 8192
#define NBLKA 196   // ceil(N_EDGES/CHUNKA)

// pack two fp32 -> two bf16 (RNE) in one uint (a=low, b=high)
__device__ inline unsigned bfpack(float a, float b) {
    unsigned ua = __builtin_bit_cast(unsigned, a);
    unsigned ub = __builtin_bit_cast(unsigned, b);
    ua = (ua + 0x7FFF + ((ua >> 16) & 1)) >> 16;
    ub = (ub + 0x7FFF + ((ub >> 16) & 1)) >> 16;
    return ua | (ub << 16);
}

// ---------------- degree histogram ----------------
__global__ void deg_kernel(const int* __restrict__ ei, int* __restrict__ deg) {
    int e = blockIdx.x * blockDim.x + threadIdx.x;
    if (e < N_EDGES) atomicAdd(&deg[ei[N_EDGES + e]], 1);
}

// ---------------- deg^(-1/2) ----------------
__global__ void dis_kernel(const int* __restrict__ deg, float* __restrict__ dis) {
    int i = blockIdx.x * blockDim.x + threadIdx.x;
    if (i < N_NODES) {
        int d = deg[i];
        dis[i] = (d > 0) ? rsqrtf((float)d) : 0.0f;
    }
}

// ---------------- exclusive scan, 2-level ----------------
__global__ void scan_block(const int* __restrict__ deg, int* __restrict__ offs,
                           int* __restrict__ bsum) {
    __shared__ int s[256];
    int tid = threadIdx.x;
    int i = blockIdx.x * 256 + tid;
    int v = (i < N_NODES) ? deg[i] : 0;
    s[tid] = v;
    __syncthreads();
#pragma unroll
    for (int off = 1; off < 256; off <<= 1) {
        int t = (tid >= off) ? s[tid - off] : 0;
        __syncthreads();
        s[tid] += t;
        __syncthreads();
    }
    if (i < N_NODES) offs[i] = s[tid] - v;
    if (tid == 255) bsum[blockIdx.x] = s[255];
}

__global__ void scan_top(int* __restrict__ bsum) {
    __shared__ int s[512];
    int tid = threadIdx.x;
    int v = (tid < NBLK) ? bsum[tid] : 0;
    s[tid] = v;
    __syncthreads();
#pragma unroll
    for (int off = 1; off < 512; off <<= 1) {
        int t = (tid >= off) ? s[tid - off] : 0;
        __syncthreads();
        s[tid] += t;
        __syncthreads();
    }
    if (tid < NBLK) bsum[tid] = s[tid] - v;
}

__global__ void scan_add(int* __restrict__ offs, const int* __restrict__ bsum) {
    int i = blockIdx.x * 256 + threadIdx.x;
    if (i < N_NODES) offs[i] += bsum[i >> 8];
}

// ---------------- CSR build pass A: bin edges by dst>>8 ----------------
__global__ __launch_bounds__(256) void binA_kernel(const int* __restrict__ ei,
                                                   const int* __restrict__ offs,
                                                   int* __restrict__ bcur,
                                                   uint2* __restrict__ epairs) {
    __shared__ int hist[NBUCK], base[NBUCK], bb[NBUCK], cur[NBUCK];
    const int t = threadIdx.x;
    const int e0 = blockIdx.x * CHUNKA;
    const int n  = min(CHUNKA, N_EDGES - e0);
    for (int i = t; i < NBUCK; i += 256) hist[i] = 0;
    __syncthreads();
    for (int i = t; i < n; i += 256) {
        int dst = ei[N_EDGES + e0 + i];
        atomicAdd(&hist[dst >> 8], 1);
    }
    __syncthreads();
    for (int i = t; i < NBUCK; i += 256) {
        base[i] = atomicAdd(&bcur[i], hist[i]);
        bb[i]   = offs[i << 8];
        cur[i]  = 0;
    }
    __syncthreads();
    for (int i = t; i < n; i += 256) {
        int src = ei[e0 + i];
        int dst = ei[N_EDGES + e0 + i];
        int b   = dst >> 8;
        int r   = atomicAdd(&cur[b], 1);
        epairs[bb[b] + base[b] + r] = make_uint2((unsigned)src, (unsigned)dst);
    }
}

// ---------------- CSR build pass B: fine counting sort within bucket ----------------
__global__ __launch_bounds__(256) void binB_kernel(const uint2* __restrict__ epairs,
                                                   const int* __restrict__ offs,
                                                   int* __restrict__ srcn) {
    __shared__ int offs_s[257];
    __shared__ int cur[256];
    const int b  = blockIdx.x;
    const int t  = threadIdx.x;
    const int n0 = b << 8;
    {
        int node = n0 + t;
        offs_s[t] = (node < N_NODES) ? offs[node] : N_EDGES;
        cur[t] = 0;
        if (t == 0) {
            int ne = n0 + 256;
            offs_s[256] = (ne < N_NODES) ? offs[ne] : N_EDGES;
        }
    }
    __syncthreads();
    const int ebeg = offs_s[0];
    const int eend = offs_s[256];
    for (int e = ebeg + t; e < eend; e += 256) {
        uint2 p = epairs[e];
        int li  = (int)p.y - n0;
        int r   = atomicAdd(&cur[li], 1);
        srcn[offs_s[li] + r] = (int)p.x;
    }
}

// ---------------- GEMM1: h1b[N,128](bf16) = (A[N,128] @ W[128,128]) * dis[n] ----------------
__global__ __launch_bounds__(256) void gemm1_kernel(const float* __restrict__ A,
                                                    const float* __restrict__ W,
                                                    const float* __restrict__ dis,
                                                    unsigned short* __restrict__ h1b) {
    __shared__ float As[32][65];
    __shared__ float Ws[32][128];
    const int t  = threadIdx.x;
    const int tj = t & 15;
    const int tn = t >> 4;
    const int node0 = blockIdx.x * 64;

    float acc[4][8];
#pragma unroll
    for (int i = 0; i < 4; i++)
#pragma unroll
        for (int j = 0; j < 8; j++) acc[i][j] = 0.0f;

    for (int kb = 0; kb < 4; ++kb) {
        {
            int n   = t >> 2;
            int kk0 = (t & 3) * 8;
            int gn  = node0 + n;
            float4 v0 = make_float4(0, 0, 0, 0), v1 = v0;
            if (gn < N_NODES) {
                const float* p = A + (size_t)gn * 128 + kb * 32 + kk0;
                v0 = *(const float4*)p;
                v1 = *(const float4*)(p + 4);
            }
            As[kk0 + 0][n] = v0.x; As[kk0 + 1][n] = v0.y;
            As[kk0 + 2][n] = v0.z; As[kk0 + 3][n] = v0.w;
            As[kk0 + 4][n] = v1.x; As[kk0 + 5][n] = v1.y;
            As[kk0 + 6][n] = v1.z; As[kk0 + 7][n] = v1.w;
        }
        {
            const float4* Wg = (const float4*)(W + (size_t)kb * 32 * 128);
            float4* Wl = (float4*)(&Ws[0][0]);
#pragma unroll
            for (int i = 0; i < 4; i++) Wl[i * 256 + t] = Wg[i * 256 + t];
        }
        __syncthreads();
#pragma unroll
        for (int kk = 0; kk < 32; ++kk) {
            float4 a  = *(const float4*)&As[kk][tn * 4];
            float4 b0 = *(const float4*)&Ws[kk][tj * 8];
            float4 b1 = *(const float4*)&Ws[kk][tj * 8 + 4];
            float av[4] = {a.x, a.y, a.z, a.w};
            float bv[8] = {b0.x, b0.y, b0.z, b0.w, b1.x, b1.y, b1.z, b1.w};
#pragma unroll
            for (int i = 0; i < 4; i++)
#pragma unroll
                for (int j = 0; j < 8; j++) acc[i][j] += av[i] * bv[j];
        }
        __syncthreads();
    }
#pragma unroll
    for (int i = 0; i < 4; i++) {
        int gn = node0 + tn * 4 + i;
        if (gn < N_NODES) {
            float dv = dis[gn];
            uint4 o;
            o.x = bfpack(acc[i][0] * dv, acc[i][1] * dv);
            o.y = bfpack(acc[i][2] * dv, acc[i][3] * dv);
            o.z = bfpack(acc[i][4] * dv, acc[i][5] * dv);
            o.w = bfpack(acc[i][6] * dv, acc[i][7] * dv);
            *(uint4*)(h1b + (size_t)gn * 128 + tj * 8) = o;
        }
    }
}

// ---------------- GEMM2: h2s[N,64] = (relu(Agg+b1) @ W2) * dis[n] ----------------
__global__ __launch_bounds__(256) void gemm2_kernel(const float* __restrict__ Agg,
                                                    const float* __restrict__ b1,
                                                    const float* __restrict__ W2,
                                                    const float* __restrict__ dis,
                                                    float* __restrict__ h2s) {
    __shared__ float As[32][65];
    __shared__ float Ws[32][64];
    const int t  = threadIdx.x;
    const int tj = t & 15;
    const int tn = t >> 4;
    const int node0 = blockIdx.x * 64;

    float acc[4][4];
#pragma unroll
    for (int i = 0; i < 4; i++)
#pragma unroll
        for (int j = 0; j < 4; j++) acc[i][j] = 0.0f;

    for (int kb = 0; kb < 4; ++kb) {
        {
            int n   = t >> 2;
            int kk0 = (t & 3) * 8;
            int gn  = node0 + n;
            float v[8];
            if (gn < N_NODES) {
                const float* p = Agg + (size_t)gn * 128 + kb * 32 + kk0;
                float4 v0 = *(const float4*)p;
                float4 v1 = *(const float4*)(p + 4);
                const float* bp = b1 + kb * 32 + kk0;
                v[0] = v0.x + bp[0]; v[1] = v0.y + bp[1];
                v[2] = v0.z + bp[2]; v[3] = v0.w + bp[3];
                v[4] = v1.x + bp[4]; v[5] = v1.y + bp[5];
                v[6] = v1.z + bp[6]; v[7] = v1.w + bp[7];
#pragma unroll
                for (int i = 0; i < 8; i++) v[i] = fmaxf(v[i], 0.0f);
            } else {
#pragma unroll
                for (int i = 0; i < 8; i++) v[i] = 0.0f;
            }
#pragma unroll
            for (int i = 0; i < 8; i++) As[kk0 + i][n] = v[i];
        }
        {
            const float4* Wg = (const float4*)(W2 + (size_t)kb * 32 * 64);
            float4* Wl = (float4*)(&Ws[0][0]);
#pragma unroll
            for (int i = 0; i < 2; i++) Wl[i * 256 + t] = Wg[i * 256 + t];
        }
        __syncthreads();
#pragma unroll
        for (int kk = 0; kk < 32; ++kk) {
            float4 a = *(const float4*)&As[kk][tn * 4];
            float4 b = *(const float4*)&Ws[kk][tj * 4];
            float av[4] = {a.x, a.y, a.z, a.w};
            float bv[4] = {b.x, b.y, b.z, b.w};
#pragma unroll
            for (int i = 0; i < 4; i++)
#pragma unroll
                for (int j = 0; j < 4; j++) acc[i][j] += av[i] * bv[j];
        }
        __syncthreads();
    }
#pragma unroll
    for (int i = 0; i < 4; i++) {
        int gn = node0 + tn * 4 + i;
        if (gn < N_NODES) {
            float dv = dis[gn];
            float* p = h2s + (size_t)gn * 64 + tj * 4;
            *(float4*)p = make_float4(acc[i][0] * dv, acc[i][1] * dv,
                                      acc[i][2] * dv, acc[i][3] * dv);
        }
    }
}

// ---------------- CSR aggregation, width 128, bf16 gather: one wave per node ----------------
__global__ __launch_bounds__(256) void agg1_kernel(const int* __restrict__ srcn,
                                                   const int* __restrict__ offs,
                                                   const int* __restrict__ deg,
                                                   const float* __restrict__ dis,
                                                   const unsigned* __restrict__ h1b,
                                                   float* __restrict__ agg) {
    int wave = (blockIdx.x * 256 + threadIdx.x) >> 6;
    int lane = threadIdx.x & 63;
    if (wave >= N_NODES) return;
    int beg = offs[wave];
    int d   = deg[wave];
    float dv = dis[wave];
    float ax = 0.0f, ay = 0.0f;
#pragma unroll 4
    for (int k = 0; k < d; ++k) {
        int src = srcn[beg + k];
        unsigned v = h1b[(size_t)src * 64 + lane];
        ax += __builtin_bit_cast(float, v << 16);
        ay += __builtin_bit_cast(float, v & 0xFFFF0000u);
    }
    ((float2*)(agg + (size_t)wave * 128))[lane] = make_float2(dv * ax, dv * ay);
}

// ---------------- CSR aggregation, width 64 fp32, + b2 -> out ----------------
__global__ __launch_bounds__(256) void agg2_kernel(const int* __restrict__ srcn,
                                                   const int* __restrict__ offs,
                                                   const int* __restrict__ deg,
                                                   const float* __restrict__ dis,
                                                   const float* __restrict__ h2s,
                                                   const float* __restrict__ b2,
                                                   float* __restrict__ out) {
    int wave = (blockIdx.x * 256 + threadIdx.x) >> 6;
    int lane = threadIdx.x & 63;
    if (wave >= N_NODES) return;
    int beg = offs[wave];
    int d   = deg[wave];
    float dv = dis[wave];
    float acc = 0.0f;
#pragma unroll 4
    for (int k = 0; k < d; ++k) {
        int src = srcn[beg + k];
        acc += h2s[(size_t)src * 64 + lane];
    }
    out[(size_t)wave * 64 + lane] = dv * acc + b2[lane];
}

extern "C" void kernel_launch(void* const* d_in, const int* in_sizes, int n_in,
                              void* d_out, int out_size, void* d_ws, size_t ws_size,
                              hipStream_t stream) {
    const float* x  = (const float*)d_in[0];
    const int*   ei = (const int*)d_in[1];
    const float* W1 = (const float*)d_in[2];
    const float* b1 = (const float*)d_in[3];
    const float* W2 = (const float*)d_in[4];
    const float* b2 = (const float*)d_in[5];
    float* out = (float*)d_out;

    char* ws = (char*)d_ws;
    int*   deg  = (int*)(ws);                          // 400 KB   @ 0
    int*   bcur = (int*)(ws + (size_t)512 * 1024);     // 1.6 KB   @ 0.5 MB
    int*   offs = (int*)(ws + (size_t)1024 * 1024);    // 400 KB   @ 1.0 MB
    float* dis  = (float*)(ws + (size_t)1536 * 1024);  // 400 KB   @ 1.5 MB
    int*   bsum = (int*)(ws + (size_t)2048 * 1024);    // 2 KB     @ 2.0 MB
    int*   srcn = (int*)(ws + (size_t)2560 * 1024);    // 6.4 MB   @ 2.5 MB
    unsigned short* h1b = (unsigned short*)(ws + (size_t)9216 * 1024);   // 25.6 MB @ 9 MB
    float* h2s  = (float*)(ws + (size_t)9216 * 1024);  // aliases h1b (dead by then)
    float* agg1 = (float*)(ws + (size_t)36 * 1024 * 1024);  // 51.2 MB @ 36 MB
    uint2* epairs = (uint2*)agg1;  // 12.8 MB, aliases agg1 (dead before agg1_kernel writes)

    hipMemsetAsync(ws, 0, (size_t)1024 * 1024, stream);  // deg + bcur

    deg_kernel<<<(N_EDGES + 255) / 256, 256, 0, stream>>>(ei, deg);
    dis_kernel<<<(N_NODES + 255) / 256, 256, 0, stream>>>(deg, dis);
    scan_block<<<NBLK, 256, 0, stream>>>(deg, offs, bsum);
    scan_top<<<1, 512, 0, stream>>>(bsum);
    scan_add<<<NBLK, 256, 0, stream>>>(offs, bsum);
    binA_kernel<<<NBLKA, 256, 0, stream>>>(ei, offs, bcur, epairs);
    binB_kernel<<<NBUCK, 256, 0, stream>>>(epairs, offs, srcn);
    gemm1_kernel<<<(N_NODES + 63) / 64, 256, 0, stream>>>(x, W1, dis, h1b);
    agg1_kernel<<<(N_NODES * 64 + 255) / 256, 256, 0, stream>>>(srcn, offs, deg, dis,
                                                                (const unsigned*)h1b, agg1);
    gemm2_kernel<<<(N_NODES + 63) / 64, 256, 0, stream>>>(agg1, b1, W2, dis, h2s);
    agg2_kernel<<<(N_NODES * 64 + 255) / 256, 256, 0, stream>>>(srcn, offs, deg, dis, h2s, b2, out);
}

// Round 6
// 405.129 us; speedup vs baseline: 3.1738x; 1.1150x over previous
//
#include <hip/hip_runtime.h>

#define N_NODES 100000
#define N_EDGES 1600000
#define NBLK 391    // ceil(N_NODES/256) for scan
#define NBUCK 391   // dst buckets of 256 nodes (dst>>8)
#define CHUNKA 8192
#define NBLKA 196   // ceil(N_EDGES/CHUNKA)

typedef __bf16 bf16x8 __attribute__((ext_vector_type(8)));
typedef float f32x4 __attribute__((ext_vector_type(4)));

// fp32 -> bf16 (RNE) as ushort
__device__ inline unsigned short bf1(float a) {
    unsigned u = __builtin_bit_cast(unsigned, a);
    u = (u + 0x7FFF + ((u >> 16) & 1)) >> 16;
    return (unsigned short)u;
}
// pack two fp32 -> two bf16 in one uint (a=low, b=high)
__device__ inline unsigned bfpack(float a, float b) {
    unsigned ua = __builtin_bit_cast(unsigned, a);
    unsigned ub = __builtin_bit_cast(unsigned, b);
    ua = (ua + 0x7FFF + ((ua >> 16) & 1)) >> 16;
    ub = (ub + 0x7FFF + ((ub >> 16) & 1)) >> 16;
    return ua | (ub << 16);
}
__device__ inline float bf2f(unsigned short u) {
    return __builtin_bit_cast(float, ((unsigned)u) << 16);
}

// ---------------- degree histogram ----------------
__global__ void deg_kernel(const int* __restrict__ ei, int* __restrict__ deg) {
    int e = blockIdx.x * blockDim.x + threadIdx.x;
    if (e < N_EDGES) atomicAdd(&deg[ei[N_EDGES + e]], 1);
}

// ---------------- deg^(-1/2) ----------------
__global__ void dis_kernel(const int* __restrict__ deg, float* __restrict__ dis) {
    int i = blockIdx.x * blockDim.x + threadIdx.x;
    if (i < N_NODES) {
        int d = deg[i];
        dis[i] = (d > 0) ? rsqrtf((float)d) : 0.0f;
    }
}

// ---------------- exclusive scan, 2-level ----------------
__global__ void scan_block(const int* __restrict__ deg, int* __restrict__ offs,
                           int* __restrict__ bsum) {
    __shared__ int s[256];
    int tid = threadIdx.x;
    int i = blockIdx.x * 256 + tid;
    int v = (i < N_NODES) ? deg[i] : 0;
    s[tid] = v;
    __syncthreads();
#pragma unroll
    for (int off = 1; off < 256; off <<= 1) {
        int t = (tid >= off) ? s[tid - off] : 0;
        __syncthreads();
        s[tid] += t;
        __syncthreads();
    }
    if (i < N_NODES) offs[i] = s[tid] - v;
    if (tid == 255) bsum[blockIdx.x] = s[255];
}

__global__ void scan_top(int* __restrict__ bsum) {
    __shared__ int s[512];
    int tid = threadIdx.x;
    int v = (tid < NBLK) ? bsum[tid] : 0;
    s[tid] = v;
    __syncthreads();
#pragma unroll
    for (int off = 1; off < 512; off <<= 1) {
        int t = (tid >= off) ? s[tid - off] : 0;
        __syncthreads();
        s[tid] += t;
        __syncthreads();
    }
    if (tid < NBLK) bsum[tid] = s[tid] - v;
}

__global__ void scan_add(int* __restrict__ offs, const int* __restrict__ bsum) {
    int i = blockIdx.x * 256 + threadIdx.x;
    if (i < N_NODES) offs[i] += bsum[i >> 8];
}

// ---------------- CSR build pass A: bin edges by dst>>8 ----------------
__global__ __launch_bounds__(256) void binA_kernel(const int* __restrict__ ei,
                                                   const int* __restrict__ offs,
                                                   int* __restrict__ bcur,
                                                   uint2* __restrict__ epairs) {
    __shared__ int hist[NBUCK], base[NBUCK], bb[NBUCK], cur[NBUCK];
    const int t = threadIdx.x;
    const int e0 = blockIdx.x * CHUNKA;
    const int n  = min(CHUNKA, N_EDGES - e0);
    for (int i = t; i < NBUCK; i += 256) hist[i] = 0;
    __syncthreads();
    for (int i = t; i < n; i += 256) {
        int dst = ei[N_EDGES + e0 + i];
        atomicAdd(&hist[dst >> 8], 1);
    }
    __syncthreads();
    for (int i = t; i < NBUCK; i += 256) {
        base[i] = atomicAdd(&bcur[i], hist[i]);
        bb[i]   = offs[i << 8];
        cur[i]  = 0;
    }
    __syncthreads();
    for (int i = t; i < n; i += 256) {
        int src = ei[e0 + i];
        int dst = ei[N_EDGES + e0 + i];
        int b   = dst >> 8;
        int r   = atomicAdd(&cur[b], 1);
        epairs[bb[b] + base[b] + r] = make_uint2((unsigned)src, (unsigned)dst);
    }
}

// ---------------- CSR build pass B: fine counting sort within bucket ----------------
__global__ __launch_bounds__(256) void binB_kernel(const uint2* __restrict__ epairs,
                                                   const int* __restrict__ offs,
                                                   int* __restrict__ srcn) {
    __shared__ int offs_s[257];
    __shared__ int cur[256];
    const int b  = blockIdx.x;
    const int t  = threadIdx.x;
    const int n0 = b << 8;
    {
        int node = n0 + t;
        offs_s[t] = (node < N_NODES) ? offs[node] : N_EDGES;
        cur[t] = 0;
        if (t == 0) {
            int ne = n0 + 256;
            offs_s[256] = (ne < N_NODES) ? offs[ne] : N_EDGES;
        }
    }
    __syncthreads();
    const int ebeg = offs_s[0];
    const int eend = offs_s[256];
    for (int e = ebeg + t; e < eend; e += 256) {
        uint2 p = epairs[e];
        int li  = (int)p.y - n0;
        int r   = atomicAdd(&cur[li], 1);
        srcn[offs_s[li] + r] = (int)p.x;
    }
}

// ---------------- W transpose + bf16: Wt[n][k] ----------------
__global__ void wtrans_kernel(const float* __restrict__ W1, const float* __restrict__ W2,
                              unsigned short* __restrict__ Wt1, unsigned short* __restrict__ Wt2) {
    int t = threadIdx.x;
    if (blockIdx.x == 0) {
        for (int i = t; i < 128 * 128; i += 256) {
            int k = i >> 7, n = i & 127;
            Wt1[n * 128 + k] = bf1(W1[i]);
        }
    } else {
        for (int i = t; i < 128 * 64; i += 256) {
            int k = i >> 6, n = i & 63;
            Wt2[n * 128 + k] = bf1(W2[i]);
        }
    }
}

// ---------------- GEMM1 (MFMA): h1b[N,128](bf16) = (x @ W1) * dis[n] ----------------
// block = 256 thr (4 waves), M-tile 64, K=128 unrolled, wave -> 32 cols
__global__ __launch_bounds__(256) void gemm1_kernel(const float* __restrict__ x,
                                                    const unsigned short* __restrict__ Wt1,
                                                    const float* __restrict__ dis,
                                                    unsigned short* __restrict__ h1b) {
    __shared__ unsigned short Asm[64][136];  // row stride 272B (16B-aligned), padded
    __shared__ float diss[64];
    const int t = threadIdx.x;
    const int node0 = blockIdx.x * 64;

    // stage A: 64x128 fp32 -> bf16 LDS; 1024 units x 8 floats = 8192 floats
#pragma unroll
    for (int c = 0; c < 4; ++c) {
        int i = c * 256 + t;            // 0..1023
        int row = i >> 4, ko = (i & 15) * 8;
        int gn = node0 + row;
        float4 v0 = make_float4(0, 0, 0, 0), v1 = v0;
        if (gn < N_NODES) {
            const float* p = x + (size_t)gn * 128 + ko;
            v0 = *(const float4*)p;
            v1 = *(const float4*)(p + 4);
        }
        uint4 o;
        o.x = bfpack(v0.x, v0.y); o.y = bfpack(v0.z, v0.w);
        o.z = bfpack(v1.x, v1.y); o.w = bfpack(v1.z, v1.w);
        *(uint4*)&Asm[row][ko] = o;
    }
    if (t < 64) {
        int gn = node0 + t;
        diss[t] = (gn < N_NODES) ? dis[gn] : 0.0f;
    }
    __syncthreads();

    const int wv = t >> 6, ln = t & 63;
    const int lc = ln & 15, q = ln >> 4;
    const int n0 = wv * 32;

    // B-frags from global (L2-hot): B[k=q*8+j][n=n0+nt*16+lc]
    bf16x8 bfr[2][4];
#pragma unroll
    for (int nt = 0; nt < 2; ++nt)
#pragma unroll
        for (int k = 0; k < 4; ++k)
            bfr[nt][k] = *(const bf16x8*)(Wt1 + (size_t)(n0 + nt * 16 + lc) * 128 + k * 32 + q * 8);

    f32x4 acc[4][2];
#pragma unroll
    for (int m = 0; m < 4; ++m)
#pragma unroll
        for (int nt = 0; nt < 2; ++nt) acc[m][nt] = (f32x4)(0.0f);

#pragma unroll
    for (int k = 0; k < 4; ++k) {
        bf16x8 af[4];
#pragma unroll
        for (int m = 0; m < 4; ++m)
            af[m] = *(const bf16x8*)&Asm[m * 16 + lc][k * 32 + q * 8];
#pragma unroll
        for (int m = 0; m < 4; ++m)
#pragma unroll
            for (int nt = 0; nt < 2; ++nt)
                acc[m][nt] = __builtin_amdgcn_mfma_f32_16x16x32_bf16(af[m], bfr[nt][k], acc[m][nt], 0, 0, 0);
    }

    // epilogue: C row = m*16 + q*4 + r, col = n0 + nt*16 + lc  [m89/m91 layout]
#pragma unroll
    for (int m = 0; m < 4; ++m)
#pragma unroll
        for (int r = 0; r < 4; ++r) {
            int lr = m * 16 + q * 4 + r;
            int gn = node0 + lr;
            if (gn < N_NODES) {
                float dv = diss[lr];
#pragma unroll
                for (int nt = 0; nt < 2; ++nt)
                    h1b[(size_t)gn * 128 + n0 + nt * 16 + lc] = bf1(acc[m][nt][r] * dv);
            }
        }
}

// ---------------- GEMM2 (MFMA): h2b[N,64](bf16) = (relu(Agg+b1) @ W2) * dis[n] ----------------
__global__ __launch_bounds__(256) void gemm2_kernel(const float* __restrict__ Agg,
                                                    const float* __restrict__ b1,
                                                    const unsigned short* __restrict__ Wt2,
                                                    const float* __restrict__ dis,
                                                    unsigned short* __restrict__ h2b) {
    __shared__ unsigned short Asm[64][136];
    __shared__ float diss[64];
    const int t = threadIdx.x;
    const int node0 = blockIdx.x * 64;

#pragma unroll
    for (int c = 0; c < 4; ++c) {
        int i = c * 256 + t;            // 0..1023
        int row = i >> 4, ko = (i & 15) * 8;
        int gn = node0 + row;
        float4 v0 = make_float4(0, 0, 0, 0), v1 = v0;
        if (gn < N_NODES) {
            const float* p = Agg + (size_t)gn * 128 + ko;
            v0 = *(const float4*)p;
            v1 = *(const float4*)(p + 4);
            float4 ba = *(const float4*)(b1 + ko);
            float4 bb = *(const float4*)(b1 + ko + 4);
            v0.x = fmaxf(v0.x + ba.x, 0.0f); v0.y = fmaxf(v0.y + ba.y, 0.0f);
            v0.z = fmaxf(v0.z + ba.z, 0.0f); v0.w = fmaxf(v0.w + ba.w, 0.0f);
            v1.x = fmaxf(v1.x + bb.x, 0.0f); v1.y = fmaxf(v1.y + bb.y, 0.0f);
            v1.z = fmaxf(v1.z + bb.z, 0.0f); v1.w = fmaxf(v1.w + bb.w, 0.0f);
        }
        uint4 o;
        o.x = bfpack(v0.x, v0.y); o.y = bfpack(v0.z, v0.w);
        o.z = bfpack(v1.x, v1.y); o.w = bfpack(v1.z, v1.w);
        *(uint4*)&Asm[row][ko] = o;
    }
    if (t < 64) {
        int gn = node0 + t;
        diss[t] = (gn < N_NODES) ? dis[gn] : 0.0f;
    }
    __syncthreads();

    const int wv = t >> 6, ln = t & 63;
    const int lc = ln & 15, q = ln >> 4;
    const int n0 = wv * 16;   // wave -> one 16-col tile

    bf16x8 bfr[4];
#pragma unroll
    for (int k = 0; k < 4; ++k)
        bfr[k] = *(const bf16x8*)(Wt2 + (size_t)(n0 + lc) * 128 + k * 32 + q * 8);

    f32x4 acc[4];
#pragma unroll
    for (int m = 0; m < 4; ++m) acc[m] = (f32x4)(0.0f);

#pragma unroll
    for (int k = 0; k < 4; ++k) {
        bf16x8 af[4];
#pragma unroll
        for (int m = 0; m < 4; ++m)
            af[m] = *(const bf16x8*)&Asm[m * 16 + lc][k * 32 + q * 8];
#pragma unroll
        for (int m = 0; m < 4; ++m)
            acc[m] = __builtin_amdgcn_mfma_f32_16x16x32_bf16(af[m], bfr[k], acc[m], 0, 0, 0);
    }

#pragma unroll
    for (int m = 0; m < 4; ++m)
#pragma unroll
        for (int r = 0; r < 4; ++r) {
            int lr = m * 16 + q * 4 + r;
            int gn = node0 + lr;
            if (gn < N_NODES) {
                float dv = diss[lr];
                h2b[(size_t)gn * 64 + n0 + lc] = bf1(acc[m][r] * dv);
            }
        }
}

// ---------------- CSR aggregation, width 128, bf16 gather: one wave per node ----------------
__global__ __launch_bounds__(256) void agg1_kernel(const int* __restrict__ srcn,
                                                   const int* __restrict__ offs,
                                                   const int* __restrict__ deg,
                                                   const float* __restrict__ dis,
                                                   const unsigned* __restrict__ h1b,
                                                   float* __restrict__ agg) {
    int wave = (blockIdx.x * 256 + threadIdx.x) >> 6;
    int lane = threadIdx.x & 63;
    if (wave >= N_NODES) return;
    int beg = offs[wave];
    int d   = deg[wave];
    float dv = dis[wave];
    float ax = 0.0f, ay = 0.0f;
#pragma unroll 4
    for (int k = 0; k < d; ++k) {
        int src = srcn[beg + k];
        unsigned v = h1b[(size_t)src * 64 + lane];
        ax += __builtin_bit_cast(float, v << 16);
        ay += __builtin_bit_cast(float, v & 0xFFFF0000u);
    }
    ((float2*)(agg + (size_t)wave * 128))[lane] = make_float2(dv * ax, dv * ay);
}

// ---------------- CSR aggregation, width 64 bf16, + b2 -> out ----------------
__global__ __launch_bounds__(256) void agg2_kernel(const int* __restrict__ srcn,
                                                   const int* __restrict__ offs,
                                                   const int* __restrict__ deg,
                                                   const float* __restrict__ dis,
                                                   const unsigned short* __restrict__ h2b,
                                                   const float* __restrict__ b2,
                                                   float* __restrict__ out) {
    int wave = (blockIdx.x * 256 + threadIdx.x) >> 6;
    int lane = threadIdx.x & 63;
    if (wave >= N_NODES) return;
    int beg = offs[wave];
    int d   = deg[wave];
    float dv = dis[wave];
    float acc = 0.0f;
#pragma unroll 4
    for (int k = 0; k < d; ++k) {
        int src = srcn[beg + k];
        acc += bf2f(h2b[(size_t)src * 64 + lane]);
    }
    out[(size_t)wave * 64 + lane] = dv * acc + b2[lane];
}

extern "C" void kernel_launch(void* const* d_in, const int* in_sizes, int n_in,
                              void* d_out, int out_size, void* d_ws, size_t ws_size,
                              hipStream_t stream) {
    const float* x  = (const float*)d_in[0];
    const int*   ei = (const int*)d_in[1];
    const float* W1 = (const float*)d_in[2];
    const float* b1 = (const float*)d_in[3];
    const float* W2 = (const float*)d_in[4];
    const float* b2 = (const float*)d_in[5];
    float* out = (float*)d_out;

    char* ws = (char*)d_ws;
    int*   deg  = (int*)(ws);                          // 400 KB   @ 0
    int*   bcur = (int*)(ws + (size_t)512 * 1024);     // 1.6 KB   @ 0.5 MB
    int*   offs = (int*)(ws + (size_t)1024 * 1024);    // 400 KB   @ 1.0 MB
    float* dis  = (float*)(ws + (size_t)1536 * 1024);  // 400 KB   @ 1.5 MB
    int*   bsum = (int*)(ws + (size_t)2048 * 1024);    // 2 KB     @ 2.0 MB
    unsigned short* Wt1 = (unsigned short*)(ws + (size_t)2176 * 1024);  // 32 KB @ 2.125 MB
    unsigned short* Wt2 = (unsigned short*)(ws + (size_t)2304 * 1024);  // 16 KB @ 2.25 MB
    int*   srcn = (int*)(ws + (size_t)2560 * 1024);    // 6.4 MB   @ 2.5 MB
    unsigned short* h1b = (unsigned short*)(ws + (size_t)9216 * 1024);  // 25.6 MB @ 9 MB
    unsigned short* h2b = (unsigned short*)(ws + (size_t)9216 * 1024);  // aliases h1b (dead by then)
    float* agg1 = (float*)(ws + (size_t)36 * 1024 * 1024);  // 51.2 MB @ 36 MB
    uint2* epairs = (uint2*)agg1;  // 12.8 MB, aliases agg1 (dead before agg1_kernel writes)

    hipMemsetAsync(ws, 0, (size_t)1024 * 1024, stream);  // deg + bcur

    deg_kernel<<<(N_EDGES + 255) / 256, 256, 0, stream>>>(ei, deg);
    dis_kernel<<<(N_NODES + 255) / 256, 256, 0, stream>>>(deg, dis);
    scan_block<<<NBLK, 256, 0, stream>>>(deg, offs, bsum);
    scan_top<<<1, 512, 0, stream>>>(bsum);
    scan_add<<<NBLK, 256, 0, stream>>>(offs, bsum);
    binA_kernel<<<NBLKA, 256, 0, stream>>>(ei, offs, bcur, epairs);
    binB_kernel<<<NBUCK, 256, 0, stream>>>(epairs, offs, srcn);
    wtrans_kernel<<<2, 256, 0, stream>>>(W1, W2, Wt1, Wt2);
    gemm1_kernel<<<(N_NODES + 63) / 64, 256, 0, stream>>>(x, Wt1, dis, h1b);
    agg1_kernel<<<(N_NODES * 64 + 255) / 256, 256, 0, stream>>>(srcn, offs, deg, dis,
                                                                (const unsigned*)h1b, agg1);
    gemm2_kernel<<<(N_NODES + 63) / 64, 256, 0, stream>>>(agg1, b1, Wt2, dis, h2b);
    agg2_kernel<<<(N_NODES * 64 + 255) / 256, 256, 0, stream>>>(srcn, offs, deg, dis, h2b, b2, out);
}

// Round 7
// 325.938 us; speedup vs baseline: 3.9449x; 1.2430x over previous
//
#include <hip/hip_runtime.h>

#define N_NODES 100000
#define N_EDGES 1600000
#define NBUCK 391   // dst buckets of 256 nodes (dst>>8)
#define CHUNKA 8192
#define NBLKA 196   // ceil(N_EDGES/CHUNKA)

typedef __bf16 bf16x8 __attribute__((ext_vector_type(8)));
typedef float f32x4 __attribute__((ext_vector_type(4)));

// fp32 -> bf16 (RNE) as ushort
__device__ inline unsigned short bf1(float a) {
    unsigned u = __builtin_bit_cast(unsigned, a);
    u = (u + 0x7FFF + ((u >> 16) & 1)) >> 16;
    return (unsigned short)u;
}
// pack two fp32 -> two bf16 in one uint (a=low, b=high)
__device__ inline unsigned bfpack(float a, float b) {
    unsigned ua = __builtin_bit_cast(unsigned, a);
    unsigned ub = __builtin_bit_cast(unsigned, b);
    ua = (ua + 0x7FFF + ((ua >> 16) & 1)) >> 16;
    ub = (ub + 0x7FFF + ((ub >> 16) & 1)) >> 16;
    return ua | (ub << 16);
}

// ---------------- bucket histogram (LDS-privatized) ----------------
__global__ __launch_bounds__(256) void bhist_kernel(const int* __restrict__ ei,
                                                    int* __restrict__ bhist) {
    __shared__ int hist[NBUCK];
    const int t = threadIdx.x;
    const int e0 = blockIdx.x * CHUNKA;
    const int n  = min(CHUNKA, N_EDGES - e0);
    for (int i = t; i < NBUCK; i += 256) hist[i] = 0;
    __syncthreads();
    for (int i = t; i < n; i += 256) {
        int dst = ei[N_EDGES + e0 + i];
        atomicAdd(&hist[dst >> 8], 1);
    }
    __syncthreads();
    for (int i = t; i < NBUCK; i += 256)
        if (hist[i]) atomicAdd(&bhist[i], hist[i]);
}

// ---------------- prep: block0 = bucket scan; blocks 1,2 = W transpose+bf16 ----------------
__global__ __launch_bounds__(512) void prep_kernel(const int* __restrict__ bhist,
                                                   int* __restrict__ boffs,
                                                   const float* __restrict__ W1,
                                                   const float* __restrict__ W2,
                                                   unsigned short* __restrict__ Wt1,
                                                   unsigned short* __restrict__ Wt2) {
    const int t = threadIdx.x;
    if (blockIdx.x == 0) {
        __shared__ int s[512];
        int v = (t < NBUCK) ? bhist[t] : 0;
        s[t] = v;
        __syncthreads();
#pragma unroll
        for (int off = 1; off < 512; off <<= 1) {
            int tv = (t >= off) ? s[t - off] : 0;
            __syncthreads();
            s[t] += tv;
            __syncthreads();
        }
        if (t < NBUCK) boffs[t] = s[t] - v;          // exclusive
        if (t == NBUCK - 1) boffs[NBUCK] = s[t];     // total = N_EDGES
    } else if (blockIdx.x == 1) {
        for (int i = t; i < 128 * 128; i += 512) {
            int k = i >> 7, n = i & 127;
            Wt1[n * 128 + k] = bf1(W1[i]);
        }
    } else {
        for (int i = t; i < 128 * 64; i += 512) {
            int k = i >> 6, n = i & 63;
            Wt2[n * 128 + k] = bf1(W2[i]);
        }
    }
}

// ---------------- CSR build pass A: scatter packed (src<<8)|(dst&255) per bucket ----------------
__global__ __launch_bounds__(256) void binA_kernel(const int* __restrict__ ei,
                                                   const int* __restrict__ boffs,
                                                   int* __restrict__ bcur,
                                                   unsigned* __restrict__ epk) {
    __shared__ int hist[NBUCK], base[NBUCK], cur[NBUCK];
    const int t = threadIdx.x;
    const int e0 = blockIdx.x * CHUNKA;
    const int n  = min(CHUNKA, N_EDGES - e0);
    for (int i = t; i < NBUCK; i += 256) hist[i] = 0;
    __syncthreads();
    for (int i = t; i < n; i += 256) {
        int dst = ei[N_EDGES + e0 + i];
        atomicAdd(&hist[dst >> 8], 1);
    }
    __syncthreads();
    for (int i = t; i < NBUCK; i += 256) {
        int h = hist[i];
        base[i] = boffs[i] + (h ? atomicAdd(&bcur[i], h) : 0);
        cur[i]  = 0;
    }
    __syncthreads();
    for (int i = t; i < n; i += 256) {
        int src = ei[e0 + i];
        int dst = ei[N_EDGES + e0 + i];
        int b   = dst >> 8;
        int r   = atomicAdd(&cur[b], 1);
        epk[base[b] + r] = ((unsigned)src << 8) | (unsigned)(dst & 255);
    }
}

// ---------------- CSR build pass B: per-bucket deg/offs/dis + fine sort ----------------
__global__ __launch_bounds__(256) void binB_kernel(const unsigned* __restrict__ epk,
                                                   const int* __restrict__ boffs,
                                                   int* __restrict__ deg,
                                                   float* __restrict__ dis,
                                                   int* __restrict__ offs,
                                                   int* __restrict__ srcn) {
    __shared__ int cnt[256], s[256], loff[256];
    const int b  = blockIdx.x;
    const int t  = threadIdx.x;
    const int n0 = b << 8;
    const int base = boffs[b];
    const int end  = boffs[b + 1];
    cnt[t] = 0;
    __syncthreads();
    for (int e = base + t; e < end; e += 256)
        atomicAdd(&cnt[epk[e] & 255u], 1);
    __syncthreads();
    // exclusive scan of cnt
    int v = cnt[t];
    s[t] = v;
    __syncthreads();
#pragma unroll
    for (int off = 1; off < 256; off <<= 1) {
        int tv = (t >= off) ? s[t - off] : 0;
        __syncthreads();
        s[t] += tv;
        __syncthreads();
    }
    loff[t] = s[t] - v;
    {
        int node = n0 + t;
        if (node < N_NODES) {
            deg[node]  = v;
            dis[node]  = (v > 0) ? rsqrtf((float)v) : 0.0f;
            offs[node] = base + loff[t];
        }
    }
    cnt[t] = 0;   // reuse as cursor
    __syncthreads();
    for (int e = base + t; e < end; e += 256) {
        unsigned p = epk[e];
        int li  = (int)(p & 255u);
        int r   = atomicAdd(&cnt[li], 1);
        srcn[base + loff[li] + r] = (int)(p >> 8);
    }
}

// ---------------- GEMM1 (MFMA): h1b[N,128](bf16) = (x @ W1) * dis[n] ----------------
__global__ __launch_bounds__(256) void gemm1_kernel(const float* __restrict__ x,
                                                    const unsigned short* __restrict__ Wt1,
                                                    const float* __restrict__ dis,
                                                    unsigned short* __restrict__ h1b) {
    __shared__ unsigned short Asm[64][136];  // row stride 272B (16B-aligned), padded
    __shared__ float diss[64];
    const int t = threadIdx.x;
    const int node0 = blockIdx.x * 64;

#pragma unroll
    for (int c = 0; c < 4; ++c) {
        int i = c * 256 + t;            // 0..1023
        int row = i >> 4, ko = (i & 15) * 8;
        int gn = node0 + row;
        float4 v0 = make_float4(0, 0, 0, 0), v1 = v0;
        if (gn < N_NODES) {
            const float* p = x + (size_t)gn * 128 + ko;
            v0 = *(const float4*)p;
            v1 = *(const float4*)(p + 4);
        }
        uint4 o;
        o.x = bfpack(v0.x, v0.y); o.y = bfpack(v0.z, v0.w);
        o.z = bfpack(v1.x, v1.y); o.w = bfpack(v1.z, v1.w);
        *(uint4*)&Asm[row][ko] = o;
    }
    if (t < 64) {
        int gn = node0 + t;
        diss[t] = (gn < N_NODES) ? dis[gn] : 0.0f;
    }
    __syncthreads();

    const int wv = t >> 6, ln = t & 63;
    const int lc = ln & 15, q = ln >> 4;
    const int n0 = wv * 32;

    bf16x8 bfr[2][4];
#pragma unroll
    for (int nt = 0; nt < 2; ++nt)
#pragma unroll
        for (int k = 0; k < 4; ++k)
            bfr[nt][k] = *(const bf16x8*)(Wt1 + (size_t)(n0 + nt * 16 + lc) * 128 + k * 32 + q * 8);

    f32x4 acc[4][2];
#pragma unroll
    for (int m = 0; m < 4; ++m)
#pragma unroll
        for (int nt = 0; nt < 2; ++nt) acc[m][nt] = (f32x4)(0.0f);

#pragma unroll
    for (int k = 0; k < 4; ++k) {
        bf16x8 af[4];
#pragma unroll
        for (int m = 0; m < 4; ++m)
            af[m] = *(const bf16x8*)&Asm[m * 16 + lc][k * 32 + q * 8];
#pragma unroll
        for (int m = 0; m < 4; ++m)
#pragma unroll
            for (int nt = 0; nt < 2; ++nt)
                acc[m][nt] = __builtin_amdgcn_mfma_f32_16x16x32_bf16(af[m], bfr[nt][k], acc[m][nt], 0, 0, 0);
    }

    // C row = m*16 + q*4 + r, col = n0 + nt*16 + lc  [m89/m91 layout]
#pragma unroll
    for (int m = 0; m < 4; ++m)
#pragma unroll
        for (int r = 0; r < 4; ++r) {
            int lr = m * 16 + q * 4 + r;
            int gn = node0 + lr;
            if (gn < N_NODES) {
                float dv = diss[lr];
#pragma unroll
                for (int nt = 0; nt < 2; ++nt)
                    h1b[(size_t)gn * 128 + n0 + nt * 16 + lc] = bf1(acc[m][nt][r] * dv);
            }
        }
}

// ---------------- GEMM2 (MFMA): h2b[N,64](bf16) = (relu(aggb+b1) @ W2) * dis[n] ----------------
// aggb is bf16 [N,128]
__global__ __launch_bounds__(256) void gemm2_kernel(const unsigned short* __restrict__ aggb,
                                                    const float* __restrict__ b1,
                                                    const unsigned short* __restrict__ Wt2,
                                                    const float* __restrict__ dis,
                                                    unsigned short* __restrict__ h2b) {
    __shared__ unsigned short Asm[64][136];
    __shared__ float diss[64];
    const int t = threadIdx.x;
    const int node0 = blockIdx.x * 64;

#pragma unroll
    for (int c = 0; c < 4; ++c) {
        int i = c * 256 + t;            // 0..1023 units of 8 cols
        int row = i >> 4, ko = (i & 15) * 8;
        int gn = node0 + row;
        uint4 o = make_uint4(0, 0, 0, 0);
        if (gn < N_NODES) {
            uint4 r = *(const uint4*)(aggb + (size_t)gn * 128 + ko);
            const float* bp = b1 + ko;
            float f0 = __builtin_bit_cast(float, r.x << 16)       + bp[0];
            float f1 = __builtin_bit_cast(float, r.x & 0xFFFF0000u) + bp[1];
            float f2 = __builtin_bit_cast(float, r.y << 16)       + bp[2];
            float f3 = __builtin_bit_cast(float, r.y & 0xFFFF0000u) + bp[3];
            float f4 = __builtin_bit_cast(float, r.z << 16)       + bp[4];
            float f5 = __builtin_bit_cast(float, r.z & 0xFFFF0000u) + bp[5];
            float f6 = __builtin_bit_cast(float, r.w << 16)       + bp[6];
            float f7 = __builtin_bit_cast(float, r.w & 0xFFFF0000u) + bp[7];
            o.x = bfpack(fmaxf(f0, 0.0f), fmaxf(f1, 0.0f));
            o.y = bfpack(fmaxf(f2, 0.0f), fmaxf(f3, 0.0f));
            o.z = bfpack(fmaxf(f4, 0.0f), fmaxf(f5, 0.0f));
            o.w = bfpack(fmaxf(f6, 0.0f), fmaxf(f7, 0.0f));
        }
        *(uint4*)&Asm[row][ko] = o;
    }
    if (t < 64) {
        int gn = node0 + t;
        diss[t] = (gn < N_NODES) ? dis[gn] : 0.0f;
    }
    __syncthreads();

    const int wv = t >> 6, ln = t & 63;
    const int lc = ln & 15, q = ln >> 4;
    const int n0 = wv * 16;

    bf16x8 bfr[4];
#pragma unroll
    for (int k = 0; k < 4; ++k)
        bfr[k] = *(const bf16x8*)(Wt2 + (size_t)(n0 + lc) * 128 + k * 32 + q * 8);

    f32x4 acc[4];
#pragma unroll
    for (int m = 0; m < 4; ++m) acc[m] = (f32x4)(0.0f);

#pragma unroll
    for (int k = 0; k < 4; ++k) {
        bf16x8 af[4];
#pragma unroll
        for (int m = 0; m < 4; ++m)
            af[m] = *(const bf16x8*)&Asm[m * 16 + lc][k * 32 + q * 8];
#pragma unroll
        for (int m = 0; m < 4; ++m)
            acc[m] = __builtin_amdgcn_mfma_f32_16x16x32_bf16(af[m], bfr[k], acc[m], 0, 0, 0);
    }

#pragma unroll
    for (int m = 0; m < 4; ++m)
#pragma unroll
        for (int r = 0; r < 4; ++r) {
            int lr = m * 16 + q * 4 + r;
            int gn = node0 + lr;
            if (gn < N_NODES) {
                float dv = diss[lr];
                h2b[(size_t)gn * 64 + n0 + lc] = bf1(acc[m][r] * dv);
            }
        }
}

// ---------------- CSR aggregation, width 128 bf16 -> bf16: one wave per node ----------------
__global__ __launch_bounds__(256) void agg1_kernel(const int* __restrict__ srcn,
                                                   const int* __restrict__ offs,
                                                   const int* __restrict__ deg,
                                                   const float* __restrict__ dis,
                                                   const unsigned* __restrict__ h1b,
                                                   unsigned* __restrict__ aggb) {
    int wave = (blockIdx.x * 256 + threadIdx.x) >> 6;
    int lane = threadIdx.x & 63;
    if (wave >= N_NODES) return;
    int beg = offs[wave];
    int d   = deg[wave];
    float dv = dis[wave];
    float ax = 0.0f, ay = 0.0f;
#pragma unroll 4
    for (int k = 0; k < d; ++k) {
        int src = srcn[beg + k];
        unsigned v = h1b[(size_t)src * 64 + lane];
        ax += __builtin_bit_cast(float, v << 16);
        ay += __builtin_bit_cast(float, v & 0xFFFF0000u);
    }
    aggb[(size_t)wave * 64 + lane] = bfpack(dv * ax, dv * ay);
}

// ---------------- CSR aggregation, width 64 bf16, + b2 -> out ----------------
__global__ __launch_bounds__(256) void agg2_kernel(const int* __restrict__ srcn,
                                                   const int* __restrict__ offs,
                                                   const int* __restrict__ deg,
                                                   const float* __restrict__ dis,
                                                   const unsigned short* __restrict__ h2b,
                                                   const float* __restrict__ b2,
                                                   float* __restrict__ out) {
    int wave = (blockIdx.x * 256 + threadIdx.x) >> 6;
    int lane = threadIdx.x & 63;
    if (wave >= N_NODES) return;
    int beg = offs[wave];
    int d   = deg[wave];
    float dv = dis[wave];
    float acc = 0.0f;
#pragma unroll 4
    for (int k = 0; k < d; ++k) {
        int src = srcn[beg + k];
        acc += __builtin_bit_cast(float, ((unsigned)h2b[(size_t)src * 64 + lane]) << 16);
    }
    out[(size_t)wave * 64 + lane] = dv * acc + b2[lane];
}

extern "C" void kernel_launch(void* const* d_in, const int* in_sizes, int n_in,
                              void* d_out, int out_size, void* d_ws, size_t ws_size,
                              hipStream_t stream) {
    const float* x  = (const float*)d_in[0];
    const int*   ei = (const int*)d_in[1];
    const float* W1 = (const float*)d_in[2];
    const float* b1 = (const float*)d_in[3];
    const float* W2 = (const float*)d_in[4];
    const float* b2 = (const float*)d_in[5];
    float* out = (float*)d_out;

    char* ws = (char*)d_ws;
    int*   bhist = (int*)(ws);                           // 1.6 KB  @ 0
    int*   bcur  = (int*)(ws + (size_t)4 * 1024);        // 1.6 KB  @ 4 KB
    int*   boffs = (int*)(ws + (size_t)8 * 1024);        // 1.6 KB  @ 8 KB
    int*   deg   = (int*)(ws + (size_t)16 * 1024);       // 400 KB  @ 16 KB
    int*   offs  = (int*)(ws + (size_t)512 * 1024);      // 400 KB  @ 512 KB
    float* dis   = (float*)(ws + (size_t)1024 * 1024);   // 400 KB  @ 1 MB
    unsigned short* Wt1 = (unsigned short*)(ws + (size_t)1536 * 1024);  // 32 KB @ 1.5 MB
    unsigned short* Wt2 = (unsigned short*)(ws + (size_t)1600 * 1024);  // 16 KB
    unsigned* epk = (unsigned*)(ws + (size_t)2560 * 1024);   // 6.4 MB @ 2.5 MB
    int*   srcn  = (int*)(ws + (size_t)9216 * 1024);     // 6.4 MB  @ 9 MB
    unsigned short* h1b = (unsigned short*)(ws + (size_t)16 * 1024 * 1024);  // 25.6 MB @ 16 MB
    unsigned short* h2b = h1b;                            // 12.8 MB, aliases h1b (dead by then)
    unsigned short* aggb = (unsigned short*)(ws + (size_t)48 * 1024 * 1024); // 25.6 MB @ 48 MB

    hipMemsetAsync(ws, 0, (size_t)8 * 1024, stream);  // bhist + bcur

    bhist_kernel<<<NBLKA, 256, 0, stream>>>(ei, bhist);
    prep_kernel<<<3, 512, 0, stream>>>(bhist, boffs, W1, W2, Wt1, Wt2);
    binA_kernel<<<NBLKA, 256, 0, stream>>>(ei, boffs, bcur, epk);
    binB_kernel<<<NBUCK, 256, 0, stream>>>(epk, boffs, deg, dis, offs, srcn);
    gemm1_kernel<<<(N_NODES + 63) / 64, 256, 0, stream>>>(x, Wt1, dis, h1b);
    agg1_kernel<<<(N_NODES * 64 + 255) / 256, 256, 0, stream>>>(srcn, offs, deg, dis,
                                                                (const unsigned*)h1b,
                                                                (unsigned*)aggb);
    gemm2_kernel<<<(N_NODES + 63) / 64, 256, 0, stream>>>(aggb, b1, Wt2, dis, h2b);
    agg2_kernel<<<(N_NODES * 64 + 255) / 256, 256, 0, stream>>>(srcn, offs, deg, dis, h2b, b2, out);
}